// Round 4
// baseline (2064.053 us; speedup 1.0000x reference)
//
#include <hip/hip_runtime.h>

typedef float f32x4 __attribute__((ext_vector_type(4)));

#define TN 2048
// LDS byte offsets
#define W1B 0u        // [129][256] f32 (row 128 = zeros)      132096 B
#define W2B 132096u   // [65][16][4] f32 (group 64 = zeros)     16640 B
#define XB  148736u   // [2064] f32 (i <-> x[i-3], zero pad)     8256 B
// total 156992 B

// ---------------- prep: repack weights into d_ws ----------------
__global__ __launch_bounds__(256)
void prep_kernel(const float* __restrict__ w1, const float* __restrict__ w2,
                 float* __restrict__ w1T, float* __restrict__ w2Q) {
    int bid = blockIdx.x;
    if (bid < 32) {
        __shared__ float tile[32][33];
        int h0 = (bid >> 2) << 5, c0 = (bid & 3) << 5;
        int tx = threadIdx.x & 31, ty = threadIdx.x >> 5;
        #pragma unroll
        for (int i = ty; i < 32; i += 8) tile[i][tx] = w1[(h0 + i) * 128 + (c0 + tx)];
        __syncthreads();
        #pragma unroll
        for (int i = ty; i < 32; i += 8) w1T[(c0 + i) * 256 + (h0 + tx)] = tile[tx][i];
    } else {
        for (int idx = threadIdx.x; idx < 65 * 64; idx += 256) {
            int l = idx >> 6, n = (idx >> 2) & 15, j = idx & 3;
            w2Q[idx] = (l < 64 && n < 10) ? w2[n * 256 + 4 * l + j] : 0.0f;
        }
    }
}

__device__ __forceinline__ void ds_load4(f32x4& d, unsigned addr) {
    asm volatile("ds_read_b128 %0, %1" : "=&v"(d) : "v"(addr));
}
#define WAIT_LGKM(N) do { asm volatile("s_waitcnt lgkmcnt(" #N ")" ::: "memory"); \
                          __builtin_amdgcn_sched_barrier(0); } while (0)

// uniform ascending-index pop from 128-bit (lo,hi) mask; pad = 128 (zero row)
__device__ __forceinline__ int pop_next(unsigned long long& lo, unsigned long long& hi) {
    bool hl = lo != 0ull, hh = hi != 0ull, have = hl || hh;
    unsigned long long sel  = hl ? lo : hi;
    unsigned long long selg = have ? sel : 1ull;
    int c = __builtin_ctzll(selg) + (hl ? 0 : 64);
    c = have ? c : 128;
    unsigned long long cl = selg & (selg - 1ull);
    lo = hl ? cl : lo;
    hi = (hl || !hh) ? hi : cl;
    return c;
}
// pop from single 64-bit mask; pad = 64 (zero group)
__device__ __forceinline__ int pop_one(unsigned long long& m) {
    bool have = m != 0ull;
    unsigned long long g = have ? m : 1ull;
    int l = have ? __builtin_ctzll(g) : 64;
    m = g & (g - 1ull);
    return l;
}

__device__ __forceinline__ void issue8(unsigned long long ma, unsigned long long mb, unsigned w1a,
        f32x4& d0, f32x4& d1, f32x4& d2, f32x4& d3,
        f32x4& d4, f32x4& d5, f32x4& d6, f32x4& d7,
        unsigned long long& olo, unsigned long long& ohi) {
    unsigned long long lo = ma, hi = mb;
    int c;
    c = pop_next(lo, hi); ds_load4(d0, w1a + ((unsigned)c << 10));
    c = pop_next(lo, hi); ds_load4(d1, w1a + ((unsigned)c << 10));
    c = pop_next(lo, hi); ds_load4(d2, w1a + ((unsigned)c << 10));
    c = pop_next(lo, hi); ds_load4(d3, w1a + ((unsigned)c << 10));
    c = pop_next(lo, hi); ds_load4(d4, w1a + ((unsigned)c << 10));
    c = pop_next(lo, hi); ds_load4(d5, w1a + ((unsigned)c << 10));
    c = pop_next(lo, hi); ds_load4(d6, w1a + ((unsigned)c << 10));
    c = pop_next(lo, hi); ds_load4(d7, w1a + ((unsigned)c << 10));
    olo = lo; ohi = hi;
}

template<int OFF>
__device__ __forceinline__ void if1_step(const float (&xw)[12],
                                         const float (&cwa)[7], const float (&cwb)[7],
                                         float& v1a, float& v1b,
                                         unsigned long long& ma, unsigned long long& mb) {
    float xca = 0.f, xcb = 0.f;
    #pragma unroll
    for (int k = 0; k < 7; ++k) {
        float xv = xw[OFF + k];
        xca = fmaf(xv, cwa[k], xca);
        xcb = fmaf(xv, cwb[k], xcb);
    }
    float na = v1a + xca, nb = v1b + xcb;
    bool sa = na >= 1.0f, sb = nb >= 1.0f;
    ma = __ballot(sa); mb = __ballot(sb);
    v1a = sa ? 0.f : na; v1b = sb ? 0.f : nb;
}

// deferred L3 consume — FP order identical to R3 (verified absmax 0.0)
__device__ __forceinline__ void l3_consume(const f32x4& q0, const f32x4& q1,
        const f32x4& q2, const f32x4& q3,
        int lp0, int lp1, int lp2, int lp3,
        unsigned long long hp0, unsigned long long hp1,
        unsigned long long hp2, unsigned long long hp3,
        float& v3, float& acc) {
    float inc3 = 0.f;
    #define GG(H, L) ((((H) >> ((L) & 63)) & 1ull) ? 1.0f : 0.0f)
    inc3 = fmaf(GG(hp0, lp0), q0.x, inc3);
    inc3 = fmaf(GG(hp1, lp0), q0.y, inc3);
    inc3 = fmaf(GG(hp2, lp0), q0.z, inc3);
    inc3 = fmaf(GG(hp3, lp0), q0.w, inc3);
    inc3 = fmaf(GG(hp0, lp1), q1.x, inc3);
    inc3 = fmaf(GG(hp1, lp1), q1.y, inc3);
    inc3 = fmaf(GG(hp2, lp1), q1.z, inc3);
    inc3 = fmaf(GG(hp3, lp1), q1.w, inc3);
    inc3 = fmaf(GG(hp0, lp2), q2.x, inc3);
    inc3 = fmaf(GG(hp1, lp2), q2.y, inc3);
    inc3 = fmaf(GG(hp2, lp2), q2.z, inc3);
    inc3 = fmaf(GG(hp3, lp2), q2.w, inc3);
    inc3 = fmaf(GG(hp0, lp3), q3.x, inc3);
    inc3 = fmaf(GG(hp1, lp3), q3.y, inc3);
    inc3 = fmaf(GG(hp2, lp3), q3.z, inc3);
    inc3 = fmaf(GG(hp3, lp3), q3.w, inc3);
    #undef GG
    float nn = v3 + inc3;
    bool ss = nn >= 1.0f;
    v3 = ss ? 0.f : nn;
    acc += ss ? 1.0f : 0.0f;
}

// one scan step: consume bank C (loads for step t), issue bank I (loads for t+1)
template<int P, bool DO_X>
__device__ __forceinline__ void step(
    unsigned w1a, unsigned w2a, unsigned xaddr,
    float (&xw)[12], const float (&cwa)[7], const float (&cwb)[7],
    float& v1a, float& v1b,
    float& v20, float& v21, float& v22, float& v23,
    float& v3, float& acc,
    f32x4& c0, f32x4& c1, f32x4& c2, f32x4& c3,
    f32x4& c4, f32x4& c5, f32x4& c6, f32x4& c7,
    unsigned long long& covlo, unsigned long long& covhi,
    f32x4& i0, f32x4& i1, f32x4& i2, f32x4& i3,
    f32x4& i4, f32x4& i5, f32x4& i6, f32x4& i7,
    unsigned long long& iovlo, unsigned long long& iovhi,
    f32x4& q0, f32x4& q1, f32x4& q2, f32x4& q3,
    int& lp0, int& lp1, int& lp2, int& lp3,
    unsigned long long& hp0, unsigned long long& hp1,
    unsigned long long& hp2, unsigned long long& hp3,
    bool& anyp, f32x4& fn)
{
    // 1. layer-1 IF for t+1 (independent; runs while a(t) is in flight)
    unsigned long long nma, nmb;
    if1_step<P + 1>(xw, cwa, cwb, v1a, v1b, nma, nmb);

    // 2. issue a(t+1) into idle bank
    issue8(nma, nmb, w1a, i0, i1, i2, i3, i4, i5, i6, i7, iovlo, iovhi);

    // 3. drain a(t) + q(t-1) + x; leave exactly the 8 newest (a(t+1)) in flight
    WAIT_LGKM(8);

    // 4. deferred L3 for step t-1
    if (anyp) l3_consume(q0, q1, q2, q3, lp0, lp1, lp2, lp3, hp0, hp1, hp2, hp3, v3, acc);
    anyp = false;

    // 5. L2 consume (ascending c), rare overflow, IF layer 2
    f32x4 inc = c0;
    inc += c1; inc += c2; inc += c3; inc += c4; inc += c5; inc += c6; inc += c7;
    {
        unsigned long long lo = covlo, hi = covhi;
        while (lo | hi) {
            int c = pop_next(lo, hi);
            f32x4 t4; ds_load4(t4, w1a + ((unsigned)c << 10));
            WAIT_LGKM(0);
            inc += t4;
        }
    }
    float n0 = v20 + inc.x, n1 = v21 + inc.y, n2 = v22 + inc.z, n3 = v23 + inc.w;
    bool s0 = n0 >= 1.0f, s1 = n1 >= 1.0f, s2 = n2 >= 1.0f, s3 = n3 >= 1.0f;
    unsigned long long h0 = __ballot(s0), h1 = __ballot(s1);
    unsigned long long h2 = __ballot(s2), h3 = __ballot(s3);
    v20 = s0 ? 0.f : n0; v21 = s1 ? 0.f : n1;
    v22 = s2 ? 0.f : n2; v23 = s3 ? 0.f : n3;

    // 6. L3: issue q(t) (<=4 groups, deferred) or rare immediate exact path
    unsigned long long anym = h0 | h1 | h2 | h3;
    if (anym) {
        unsigned long long m = anym;
        int l0 = pop_one(m), l1 = pop_one(m), l2 = pop_one(m), l3 = pop_one(m);
        if (m == 0ull) {
            ds_load4(q0, w2a + ((unsigned)l0 << 8));
            ds_load4(q1, w2a + ((unsigned)l1 << 8));
            ds_load4(q2, w2a + ((unsigned)l2 << 8));
            ds_load4(q3, w2a + ((unsigned)l3 << 8));
            lp0 = l0; lp1 = l1; lp2 = l2; lp3 = l3;
            hp0 = h0; hp1 = h1; hp2 = h2; hp3 = h3;
            anyp = true;
        } else {
            float inc3 = 0.f;
            unsigned long long mm = anym;
            while (mm) {
                int l = pop_one(mm);
                f32x4 q; ds_load4(q, w2a + ((unsigned)l << 8));
                WAIT_LGKM(0);
                inc3 += ((h0 >> l) & 1ull) ? q.x : 0.0f;
                inc3 += ((h1 >> l) & 1ull) ? q.y : 0.0f;
                inc3 += ((h2 >> l) & 1ull) ? q.z : 0.0f;
                inc3 += ((h3 >> l) & 1ull) ? q.w : 0.0f;
            }
            float nn = v3 + inc3;
            bool ss = nn >= 1.0f;
            v3 = ss ? 0.f : nn;
            acc += ss ? 1.0f : 0.0f;
        }
    }

    // 7. x-window prefetch (once per 4 steps; drained by next step's WAIT(8))
    if (DO_X) ds_load4(fn, xaddr);
}

// ---------------- main: one wave per batch, depth-1 pipelined scan ----------------
__global__ __launch_bounds__(256, 1)
void snn_main(const float* __restrict__ x,
              const float* __restrict__ convw,
              const float* __restrict__ w1Tg,
              const float* __restrict__ w2Qg,
              float* __restrict__ out) {
    extern __shared__ float lds[];
    const int b = blockIdx.x;
    const int tid = threadIdx.x;

    {   // stage: w1T (+ zero row), w2Q, x
        const float4* s4 = (const float4*)w1Tg;
        float4* d4 = (float4*)lds;
        for (int i = tid; i < 8192; i += 256) d4[i] = s4[i];
        if (tid < 64) d4[8192 + tid] = make_float4(0.f, 0.f, 0.f, 0.f);
        const float4* s2 = (const float4*)w2Qg;
        float4* d2 = (float4*)(lds + W2B / 4);
        for (int i = tid; i < 1040; i += 256) d2[i] = s2[i];
        float* xL = lds + XB / 4;
        for (int i = tid; i < 2064; i += 256) {
            int l = i - 3;
            xL[i] = (l >= 0 && l < TN) ? x[b * TN + l] : 0.0f;
        }
    }
    __syncthreads();
    if (tid >= 64) return;
    const int lane = tid;

    const unsigned ldsbase = (unsigned)(uintptr_t)(void*)lds;
    const unsigned w1a = ldsbase + W1B + (unsigned)lane * 16u;          // + (c<<10)
    const unsigned w2a = ldsbase + W2B + (unsigned)(lane & 15) * 16u;   // + (l<<8)
    const unsigned xa  = ldsbase + XB;

    float cwa[7], cwb[7];
    #pragma unroll
    for (int k = 0; k < 7; ++k) {
        cwa[k] = convw[lane * 7 + k];
        cwb[k] = convw[(lane + 64) * 7 + k];
    }

    float v1a = 0.f, v1b = 0.f;
    float v20 = 0.f, v21 = 0.f, v22 = 0.f, v23 = 0.f;   // h = 4*lane + j
    float v3 = 0.f, acc = 0.f;

    float xw[12];
    {
        const float* xL = lds + XB / 4;
        float4 f0 = *(const float4*)(xL + 0);
        float4 f1 = *(const float4*)(xL + 4);
        float4 f2 = *(const float4*)(xL + 8);
        xw[0]=f0.x; xw[1]=f0.y; xw[2]=f0.z; xw[3]=f0.w;
        xw[4]=f1.x; xw[5]=f1.y; xw[6]=f1.z; xw[7]=f1.w;
        xw[8]=f2.x; xw[9]=f2.y; xw[10]=f2.z; xw[11]=f2.w;
    }

    // pipeline registers — ALL NAMED (no arrays -> no scratch)
    f32x4 A0=0.f,A1=0.f,A2=0.f,A3=0.f,A4=0.f,A5=0.f,A6=0.f,A7=0.f;
    f32x4 B0=0.f,B1=0.f,B2=0.f,B3=0.f,B4=0.f,B5=0.f,B6=0.f,B7=0.f;
    f32x4 Q0=0.f,Q1=0.f,Q2=0.f,Q3=0.f,fn=0.f;
    unsigned long long ovAlo=0, ovAhi=0, ovBlo=0, ovBhi=0;
    int lp0=64, lp1=64, lp2=64, lp3=64;
    unsigned long long hp0=0, hp1=0, hp2=0, hp3=0;
    bool anyp = false;

    WAIT_LGKM(0);           // zero the count baseline before counted waits
    {   // prologue: IF1(0), issue a(0) into bank A
        unsigned long long m0, m1;
        if1_step<0>(xw, cwa, cwb, v1a, v1b, m0, m1);
        issue8(m0, m1, w1a, A0,A1,A2,A3,A4,A5,A6,A7, ovAlo, ovAhi);
    }

    #pragma unroll 1
    for (int tb = 0; tb < TN; tb += 4) {
        unsigned xaddr = xa + (unsigned)(tb + 12) * 4u;
        step<0,true >(w1a,w2a,xaddr, xw,cwa,cwb, v1a,v1b, v20,v21,v22,v23, v3,acc,
                      A0,A1,A2,A3,A4,A5,A6,A7, ovAlo,ovAhi,
                      B0,B1,B2,B3,B4,B5,B6,B7, ovBlo,ovBhi,
                      Q0,Q1,Q2,Q3, lp0,lp1,lp2,lp3, hp0,hp1,hp2,hp3, anyp, fn);
        step<1,false>(w1a,w2a,0u, xw,cwa,cwb, v1a,v1b, v20,v21,v22,v23, v3,acc,
                      B0,B1,B2,B3,B4,B5,B6,B7, ovBlo,ovBhi,
                      A0,A1,A2,A3,A4,A5,A6,A7, ovAlo,ovAhi,
                      Q0,Q1,Q2,Q3, lp0,lp1,lp2,lp3, hp0,hp1,hp2,hp3, anyp, fn);
        step<2,false>(w1a,w2a,0u, xw,cwa,cwb, v1a,v1b, v20,v21,v22,v23, v3,acc,
                      A0,A1,A2,A3,A4,A5,A6,A7, ovAlo,ovAhi,
                      B0,B1,B2,B3,B4,B5,B6,B7, ovBlo,ovBhi,
                      Q0,Q1,Q2,Q3, lp0,lp1,lp2,lp3, hp0,hp1,hp2,hp3, anyp, fn);
        step<3,false>(w1a,w2a,0u, xw,cwa,cwb, v1a,v1b, v20,v21,v22,v23, v3,acc,
                      B0,B1,B2,B3,B4,B5,B6,B7, ovBlo,ovBhi,
                      A0,A1,A2,A3,A4,A5,A6,A7, ovAlo,ovAhi,
                      Q0,Q1,Q2,Q3, lp0,lp1,lp2,lp3, hp0,hp1,hp2,hp3, anyp, fn);
        // shift window by 4 (fn drained by step<1>'s WAIT(8))
        #pragma unroll
        for (int i = 0; i < 8; ++i) xw[i] = xw[i + 4];
        xw[8] = fn.x; xw[9] = fn.y; xw[10] = fn.z; xw[11] = fn.w;
    }

    // epilogue: finish deferred L3 for t = 2047
    WAIT_LGKM(0);
    if (anyp) l3_consume(Q0,Q1,Q2,Q3, lp0,lp1,lp2,lp3, hp0,hp1,hp2,hp3, v3, acc);

    if (lane < 10) out[b * 10 + lane] = acc * (1.0f / 2048.0f);
}

extern "C" void kernel_launch(void* const* d_in, const int* in_sizes, int n_in,
                              void* d_out, int out_size, void* d_ws, size_t ws_size,
                              hipStream_t stream) {
    const float* x     = (const float*)d_in[0];
    const float* convw = (const float*)d_in[1];
    const float* w1    = (const float*)d_in[2];
    const float* w2    = (const float*)d_in[3];
    float* w1T = (float*)d_ws;                 // 131072 B
    float* w2Q = (float*)d_ws + 32768;         //  16640 B

    prep_kernel<<<33, 256, 0, stream>>>(w1, w2, w1T, w2Q);

    const size_t ldsz = 156992;   // bytes
    (void)hipFuncSetAttribute(reinterpret_cast<const void*>(snn_main),
                              hipFuncAttributeMaxDynamicSharedMemorySize, (int)ldsz);
    snn_main<<<128, 256, ldsz, stream>>>(x, convw, w1T, w2Q, (float*)d_out);
}

// Round 5
// 1396.777 us; speedup vs baseline: 1.4777x; 1.4777x over previous
//
#include <hip/hip_runtime.h>

typedef float f32x4 __attribute__((ext_vector_type(4)));

#define TN 2048
// LDS byte offsets
#define W1B 0u        // [129][256] f32 (row 128 = zeros)      132096 B
#define W2B 132096u   // [65][16][4] f32 (group 64 = zeros)     16640 B
#define XB  148736u   // [2064] f32 (i <-> x[i-3], zero pad)     8256 B
// total 156992 B

// ---------------- prep: repack weights into d_ws ----------------
__global__ __launch_bounds__(256)
void prep_kernel(const float* __restrict__ w1, const float* __restrict__ w2,
                 float* __restrict__ w1T, float* __restrict__ w2Q) {
    int bid = blockIdx.x;
    if (bid < 32) {
        __shared__ float tile[32][33];
        int h0 = (bid >> 2) << 5, c0 = (bid & 3) << 5;
        int tx = threadIdx.x & 31, ty = threadIdx.x >> 5;
        #pragma unroll
        for (int i = ty; i < 32; i += 8) tile[i][tx] = w1[(h0 + i) * 128 + (c0 + tx)];
        __syncthreads();
        #pragma unroll
        for (int i = ty; i < 32; i += 8) w1T[(c0 + i) * 256 + (h0 + tx)] = tile[tx][i];
    } else {
        for (int idx = threadIdx.x; idx < 65 * 64; idx += 256) {
            int l = idx >> 6, n = (idx >> 2) & 15, j = idx & 3;
            w2Q[idx] = (l < 64 && n < 10) ? w2[n * 256 + 4 * l + j] : 0.0f;
        }
    }
}

// 4 batched b128 loads + ONE wait, in one asm block: cannot be sunk or split.
__device__ __forceinline__ void ds_gather4(f32x4& r0, f32x4& r1, f32x4& r2, f32x4& r3,
                                           unsigned a0, unsigned a1, unsigned a2, unsigned a3) {
    asm volatile("ds_read_b128 %0, %4\n\t"
                 "ds_read_b128 %1, %5\n\t"
                 "ds_read_b128 %2, %6\n\t"
                 "ds_read_b128 %3, %7\n\t"
                 "s_waitcnt lgkmcnt(0)"
                 : "=&v"(r0), "=&v"(r1), "=&v"(r2), "=&v"(r3)
                 : "v"(a0), "v"(a1), "v"(a2), "v"(a3));
}
// issue-only variant (no wait) — consumer must wait explicitly (deferred L3)
__device__ __forceinline__ void ds_issue4(f32x4& r0, f32x4& r1, f32x4& r2, f32x4& r3,
                                          unsigned a0, unsigned a1, unsigned a2, unsigned a3) {
    asm volatile("ds_read_b128 %0, %4\n\t"
                 "ds_read_b128 %1, %5\n\t"
                 "ds_read_b128 %2, %6\n\t"
                 "ds_read_b128 %3, %7"
                 : "=&v"(r0), "=&v"(r1), "=&v"(r2), "=&v"(r3)
                 : "v"(a0), "v"(a1), "v"(a2), "v"(a3));
}
__device__ __forceinline__ void ds_load4(f32x4& d, unsigned addr) {
    asm volatile("ds_read_b128 %0, %1" : "=&v"(d) : "v"(addr));
}
#define WAIT0 do { asm volatile("s_waitcnt lgkmcnt(0)" ::: "memory"); \
                   __builtin_amdgcn_sched_barrier(0); } while (0)

// ascending-index pop from 128-bit (lo,hi) mask; pad = 128 (zero row). [R3-validated]
__device__ __forceinline__ int pop_next(unsigned long long& lo, unsigned long long& hi) {
    bool hl = lo != 0ull, hh = hi != 0ull, have = hl || hh;
    unsigned long long sel  = hl ? lo : hi;
    unsigned long long selg = have ? sel : 1ull;
    int c = __builtin_ctzll(selg) + (hl ? 0 : 64);
    c = have ? c : 128;
    unsigned long long cl = selg & (selg - 1ull);
    lo = hl ? cl : lo;
    hi = (hl || !hh) ? hi : cl;
    return c;
}
// pop from single 64-bit mask; pad = 64 (zero group). [R3-validated]
__device__ __forceinline__ int pop_one(unsigned long long& m) {
    bool have = m != 0ull;
    unsigned long long g = have ? m : 1ull;
    int l = have ? __builtin_ctzll(g) : 64;
    m = g & (g - 1ull);
    return l;
}

template<int OFF>
__device__ __forceinline__ void if1_step(const float (&xw)[12],
                                         const float (&cwa)[7], const float (&cwb)[7],
                                         float& v1a, float& v1b,
                                         unsigned long long& ma, unsigned long long& mb) {
    float xca = 0.f, xcb = 0.f;
    #pragma unroll
    for (int k = 0; k < 7; ++k) {
        float xv = xw[OFF + k];
        xca = fmaf(xv, cwa[k], xca);
        xcb = fmaf(xv, cwb[k], xcb);
    }
    float na = v1a + xca, nb = v1b + xcb;
    bool sa = na >= 1.0f, sb = nb >= 1.0f;
    ma = __ballot(sa); mb = __ballot(sb);
    v1a = sa ? 0.f : na; v1b = sb ? 0.f : nb;
}

// deferred L3 consume — FP order identical to R3/R4 (verified absmax 0.0)
__device__ __forceinline__ void l3_consume(const f32x4& q0, const f32x4& q1,
        const f32x4& q2, const f32x4& q3,
        int lp0, int lp1, int lp2, int lp3,
        unsigned long long hp0, unsigned long long hp1,
        unsigned long long hp2, unsigned long long hp3,
        float& v3, float& acc) {
    float inc3 = 0.f;
    #define GG(H, L) ((((H) >> ((L) & 63)) & 1ull) ? 1.0f : 0.0f)
    inc3 = fmaf(GG(hp0, lp0), q0.x, inc3);
    inc3 = fmaf(GG(hp1, lp0), q0.y, inc3);
    inc3 = fmaf(GG(hp2, lp0), q0.z, inc3);
    inc3 = fmaf(GG(hp3, lp0), q0.w, inc3);
    inc3 = fmaf(GG(hp0, lp1), q1.x, inc3);
    inc3 = fmaf(GG(hp1, lp1), q1.y, inc3);
    inc3 = fmaf(GG(hp2, lp1), q1.z, inc3);
    inc3 = fmaf(GG(hp3, lp1), q1.w, inc3);
    inc3 = fmaf(GG(hp0, lp2), q2.x, inc3);
    inc3 = fmaf(GG(hp1, lp2), q2.y, inc3);
    inc3 = fmaf(GG(hp2, lp2), q2.z, inc3);
    inc3 = fmaf(GG(hp3, lp2), q2.w, inc3);
    inc3 = fmaf(GG(hp0, lp3), q3.x, inc3);
    inc3 = fmaf(GG(hp1, lp3), q3.y, inc3);
    inc3 = fmaf(GG(hp2, lp3), q3.z, inc3);
    inc3 = fmaf(GG(hp3, lp3), q3.w, inc3);
    #undef GG
    float nn = v3 + inc3;
    bool ss = nn >= 1.0f;
    v3 = ss ? 0.f : nn;
    acc += ss ? 1.0f : 0.0f;
}

// one scan step (R1 structure + batched L2 + deferred L3)
template<int OFF>
__device__ __forceinline__ void step(
    unsigned w1a, unsigned w2a,
    float (&xw)[12], const float (&cwa)[7], const float (&cwb)[7],
    float& v1a, float& v1b,
    float& v20, float& v21, float& v22, float& v23,
    float& v3, float& acc,
    f32x4& Q0, f32x4& Q1, f32x4& Q2, f32x4& Q3,
    int& lp0, int& lp1, int& lp2, int& lp3,
    unsigned long long& hp0, unsigned long long& hp1,
    unsigned long long& hp2, unsigned long long& hp3,
    bool& anyp)
{
    // ---- layer 1 ----
    unsigned long long ma, mb;
    if1_step<OFF>(xw, cwa, cwb, v1a, v1b, ma, mb);

    // ---- layer 2: 4-wide batched gather, ascending c, pads hit zero row ----
    f32x4 inc = {0.f, 0.f, 0.f, 0.f};
    {
        unsigned long long lo = ma, hi = mb;
        while (lo | hi) {
            int c0 = pop_next(lo, hi);
            int c1 = pop_next(lo, hi);
            int c2 = pop_next(lo, hi);
            int c3 = pop_next(lo, hi);
            f32x4 r0, r1, r2, r3;
            ds_gather4(r0, r1, r2, r3,
                       w1a + ((unsigned)c0 << 10), w1a + ((unsigned)c1 << 10),
                       w1a + ((unsigned)c2 << 10), w1a + ((unsigned)c3 << 10));
            inc += r0; inc += r1; inc += r2; inc += r3;
        }
    }
    float n0 = v20 + inc.x, n1 = v21 + inc.y, n2 = v22 + inc.z, n3 = v23 + inc.w;
    bool s0 = n0 >= 1.0f, s1 = n1 >= 1.0f, s2 = n2 >= 1.0f, s3 = n3 >= 1.0f;
    unsigned long long h0 = __ballot(s0), h1 = __ballot(s1);
    unsigned long long h2 = __ballot(s2), h3 = __ballot(s3);
    v20 = s0 ? 0.f : n0; v21 = s1 ? 0.f : n1;
    v22 = s2 ? 0.f : n2; v23 = s3 ? 0.f : n3;

    // ---- layer 3: consume deferred q(t-1), then issue q(t) ----
    unsigned long long anym = h0 | h1 | h2 | h3;
    if (anyp) {
        WAIT0;   // q(t-1) had a full step in flight -> effectively free
        l3_consume(Q0, Q1, Q2, Q3, lp0, lp1, lp2, lp3, hp0, hp1, hp2, hp3, v3, acc);
    }
    anyp = false;
    if (anym) {
        unsigned long long m = anym;
        int l0 = pop_one(m), l1 = pop_one(m), l2 = pop_one(m), l3 = pop_one(m);
        if (m == 0ull) {
            ds_issue4(Q0, Q1, Q2, Q3,
                      w2a + ((unsigned)l0 << 8), w2a + ((unsigned)l1 << 8),
                      w2a + ((unsigned)l2 << 8), w2a + ((unsigned)l3 << 8));
            lp0 = l0; lp1 = l1; lp2 = l2; lp3 = l3;
            hp0 = h0; hp1 = h1; hp2 = h2; hp3 = h3;
            anyp = true;
        } else {    // rare >4 groups: immediate exact-order path [R3-validated]
            float inc3 = 0.f;
            unsigned long long mm = anym;
            while (mm) {
                int l = pop_one(mm);
                f32x4 q; ds_load4(q, w2a + ((unsigned)l << 8));
                WAIT0;
                inc3 += ((h0 >> l) & 1ull) ? q.x : 0.0f;
                inc3 += ((h1 >> l) & 1ull) ? q.y : 0.0f;
                inc3 += ((h2 >> l) & 1ull) ? q.z : 0.0f;
                inc3 += ((h3 >> l) & 1ull) ? q.w : 0.0f;
            }
            float nn = v3 + inc3;
            bool ss = nn >= 1.0f;
            v3 = ss ? 0.f : nn;
            acc += ss ? 1.0f : 0.0f;
        }
    }
}

// ---------------- main: one wave per batch ----------------
__global__ __launch_bounds__(256, 1)
void snn_main(const float* __restrict__ x,
              const float* __restrict__ convw,
              const float* __restrict__ w1Tg,
              const float* __restrict__ w2Qg,
              float* __restrict__ out) {
    extern __shared__ float lds[];
    const int b = blockIdx.x;
    const int tid = threadIdx.x;

    {   // stage: w1T (+ zero row), w2Q (+ zero group), x
        const float4* s4 = (const float4*)w1Tg;
        float4* d4 = (float4*)lds;
        for (int i = tid; i < 8192; i += 256) d4[i] = s4[i];
        if (tid < 64) d4[8192 + tid] = make_float4(0.f, 0.f, 0.f, 0.f);
        const float4* s2 = (const float4*)w2Qg;
        float4* d2 = (float4*)(lds + W2B / 4);
        for (int i = tid; i < 1040; i += 256) d2[i] = s2[i];
        float* xL = lds + XB / 4;
        for (int i = tid; i < 2064; i += 256) {
            int l = i - 3;
            xL[i] = (l >= 0 && l < TN) ? x[b * TN + l] : 0.0f;
        }
    }
    __syncthreads();
    if (tid >= 64) return;
    const int lane = tid;

    const unsigned ldsbase = (unsigned)(uintptr_t)(void*)lds;
    const unsigned w1a = ldsbase + W1B + (unsigned)lane * 16u;          // + (c<<10)
    const unsigned w2a = ldsbase + W2B + (unsigned)(lane & 15) * 16u;   // + (l<<8)

    float cwa[7], cwb[7];
    #pragma unroll
    for (int k = 0; k < 7; ++k) {
        cwa[k] = convw[lane * 7 + k];
        cwb[k] = convw[(lane + 64) * 7 + k];
    }

    float v1a = 0.f, v1b = 0.f;
    float v20 = 0.f, v21 = 0.f, v22 = 0.f, v23 = 0.f;   // h = 4*lane + j
    float v3 = 0.f, acc = 0.f;

    float xw[12];
    {
        const float* xL = lds + XB / 4;
        float4 f0 = *(const float4*)(xL + 0);
        float4 f1 = *(const float4*)(xL + 4);
        float4 f2 = *(const float4*)(xL + 8);
        xw[0]=f0.x; xw[1]=f0.y; xw[2]=f0.z; xw[3]=f0.w;
        xw[4]=f1.x; xw[5]=f1.y; xw[6]=f1.z; xw[7]=f1.w;
        xw[8]=f2.x; xw[9]=f2.y; xw[10]=f2.z; xw[11]=f2.w;
    }

    // deferred-L3 state (named regs only)
    f32x4 Q0=0.f, Q1=0.f, Q2=0.f, Q3=0.f;
    int lp0=64, lp1=64, lp2=64, lp3=64;
    unsigned long long hp0=0, hp1=0, hp2=0, hp3=0;
    bool anyp = false;

    const float* xL = lds + XB / 4;
    #pragma unroll 1
    for (int tb = 0; tb < TN; tb += 4) {
        float4 fn = *(const float4*)(xL + tb + 12);   // prefetch next quad

        step<0>(w1a, w2a, xw, cwa, cwb, v1a, v1b, v20, v21, v22, v23, v3, acc,
                Q0, Q1, Q2, Q3, lp0, lp1, lp2, lp3, hp0, hp1, hp2, hp3, anyp);
        step<1>(w1a, w2a, xw, cwa, cwb, v1a, v1b, v20, v21, v22, v23, v3, acc,
                Q0, Q1, Q2, Q3, lp0, lp1, lp2, lp3, hp0, hp1, hp2, hp3, anyp);
        step<2>(w1a, w2a, xw, cwa, cwb, v1a, v1b, v20, v21, v22, v23, v3, acc,
                Q0, Q1, Q2, Q3, lp0, lp1, lp2, lp3, hp0, hp1, hp2, hp3, anyp);
        step<3>(w1a, w2a, xw, cwa, cwb, v1a, v1b, v20, v21, v22, v23, v3, acc,
                Q0, Q1, Q2, Q3, lp0, lp1, lp2, lp3, hp0, hp1, hp2, hp3, anyp);

        #pragma unroll
        for (int i = 0; i < 8; ++i) xw[i] = xw[i + 4];
        xw[8] = fn.x; xw[9] = fn.y; xw[10] = fn.z; xw[11] = fn.w;
    }

    // epilogue: finish deferred L3 for t = 2047
    if (anyp) {
        WAIT0;
        l3_consume(Q0, Q1, Q2, Q3, lp0, lp1, lp2, lp3, hp0, hp1, hp2, hp3, v3, acc);
    }

    if (lane < 10) out[b * 10 + lane] = acc * (1.0f / 2048.0f);
}

extern "C" void kernel_launch(void* const* d_in, const int* in_sizes, int n_in,
                              void* d_out, int out_size, void* d_ws, size_t ws_size,
                              hipStream_t stream) {
    const float* x     = (const float*)d_in[0];
    const float* convw = (const float*)d_in[1];
    const float* w1    = (const float*)d_in[2];
    const float* w2    = (const float*)d_in[3];
    float* w1T = (float*)d_ws;                 // 131072 B
    float* w2Q = (float*)d_ws + 32768;         //  16640 B

    prep_kernel<<<33, 256, 0, stream>>>(w1, w2, w1T, w2Q);

    const size_t ldsz = 156992;   // bytes
    (void)hipFuncSetAttribute(reinterpret_cast<const void*>(snn_main),
                              hipFuncAttributeMaxDynamicSharedMemorySize, (int)ldsz);
    snn_main<<<128, 256, ldsz, stream>>>(x, convw, w1T, w2Q, (float*)d_out);
}

// Round 6
// 1296.629 us; speedup vs baseline: 1.5919x; 1.0772x over previous
//
#include <hip/hip_runtime.h>

typedef float f32x4 __attribute__((ext_vector_type(4)));

#define TN 2048
// LDS byte offsets
#define W1B 0u        // [129][256] f32 (row 128 = zeros)      132096 B
#define W2B 132096u   // [65][16][4] f32 (group 64 = zeros)     16640 B
#define XB  148736u   // [2064] f32 (i <-> x[i-3], zero pad)     8256 B
// total 156992 B

// ---------------- prep: repack weights into d_ws ----------------
__global__ __launch_bounds__(256)
void prep_kernel(const float* __restrict__ w1, const float* __restrict__ w2,
                 float* __restrict__ w1T, float* __restrict__ w2Q) {
    int bid = blockIdx.x;
    if (bid < 32) {
        __shared__ float tile[32][33];
        int h0 = (bid >> 2) << 5, c0 = (bid & 3) << 5;
        int tx = threadIdx.x & 31, ty = threadIdx.x >> 5;
        #pragma unroll
        for (int i = ty; i < 32; i += 8) tile[i][tx] = w1[(h0 + i) * 128 + (c0 + tx)];
        __syncthreads();
        #pragma unroll
        for (int i = ty; i < 32; i += 8) w1T[(c0 + i) * 256 + (h0 + tx)] = tile[tx][i];
    } else {
        for (int idx = threadIdx.x; idx < 65 * 64; idx += 256) {
            int l = idx >> 6, n = (idx >> 2) & 15, j = idx & 3;
            w2Q[idx] = (l < 64 && n < 10) ? w2[n * 256 + 4 * l + j] : 0.0f;
        }
    }
}

// ---- asm helpers ----
__device__ __forceinline__ void ds_load4(f32x4& d, unsigned addr) {
    asm volatile("ds_read_b128 %0, %1" : "=&v"(d) : "v"(addr));
}
__device__ __forceinline__ void ds_issue4(f32x4& r0, f32x4& r1, f32x4& r2, f32x4& r3,
                                          unsigned a0, unsigned a1, unsigned a2, unsigned a3) {
    asm volatile("ds_read_b128 %0, %4\n\t"
                 "ds_read_b128 %1, %5\n\t"
                 "ds_read_b128 %2, %6\n\t"
                 "ds_read_b128 %3, %7"
                 : "=&v"(r0), "=&v"(r1), "=&v"(r2), "=&v"(r3)
                 : "v"(a0), "v"(a1), "v"(a2), "v"(a3));
}
__device__ __forceinline__ void ds_issue8(
        f32x4& r0, f32x4& r1, f32x4& r2, f32x4& r3,
        f32x4& r4, f32x4& r5, f32x4& r6, f32x4& r7,
        unsigned a0, unsigned a1, unsigned a2, unsigned a3,
        unsigned a4, unsigned a5, unsigned a6, unsigned a7) {
    asm volatile("ds_read_b128 %0, %8\n\t"
                 "ds_read_b128 %1, %9\n\t"
                 "ds_read_b128 %2, %10\n\t"
                 "ds_read_b128 %3, %11\n\t"
                 "ds_read_b128 %4, %12\n\t"
                 "ds_read_b128 %5, %13\n\t"
                 "ds_read_b128 %6, %14\n\t"
                 "ds_read_b128 %7, %15"
                 : "=&v"(r0), "=&v"(r1), "=&v"(r2), "=&v"(r3),
                   "=&v"(r4), "=&v"(r5), "=&v"(r6), "=&v"(r7)
                 : "v"(a0), "v"(a1), "v"(a2), "v"(a3),
                   "v"(a4), "v"(a5), "v"(a6), "v"(a7));
}
#define WAIT0 do { asm volatile("s_waitcnt lgkmcnt(0)" ::: "memory"); \
                   __builtin_amdgcn_sched_barrier(0); } while (0)

__device__ __forceinline__ int mbcnt64(unsigned long long m) {
    return (int)__builtin_amdgcn_mbcnt_hi((unsigned)(m >> 32),
               __builtin_amdgcn_mbcnt_lo((unsigned)m, 0u));
}

// serial fallback pop (cold path only) [R3/R5-validated]
__device__ __forceinline__ int pop_next(unsigned long long& lo, unsigned long long& hi) {
    bool hl = lo != 0ull, hh = hi != 0ull, have = hl || hh;
    unsigned long long sel  = hl ? lo : hi;
    unsigned long long selg = have ? sel : 1ull;
    int c = __builtin_ctzll(selg) + (hl ? 0 : 64);
    c = have ? c : 128;
    unsigned long long cl = selg & (selg - 1ull);
    lo = hl ? cl : lo;
    hi = (hl || !hh) ? hi : cl;
    return c;
}

// deferred L3 consume: slots ascending, j ascending — FP order == validated R5 path
__device__ __forceinline__ void l3_consume(const f32x4& q0, const f32x4& q1,
        const f32x4& q2, const f32x4& q3,
        int sp0, int sp1, int sp2, int sp3,
        float& v3, float& acc) {
    float inc3 = 0.f;
    #define GB(SP, J) ((((SP) >> (J)) & 1) ? 1.0f : 0.0f)
    inc3 = fmaf(GB(sp0, 0), q0.x, inc3);
    inc3 = fmaf(GB(sp0, 1), q0.y, inc3);
    inc3 = fmaf(GB(sp0, 2), q0.z, inc3);
    inc3 = fmaf(GB(sp0, 3), q0.w, inc3);
    inc3 = fmaf(GB(sp1, 0), q1.x, inc3);
    inc3 = fmaf(GB(sp1, 1), q1.y, inc3);
    inc3 = fmaf(GB(sp1, 2), q1.z, inc3);
    inc3 = fmaf(GB(sp1, 3), q1.w, inc3);
    inc3 = fmaf(GB(sp2, 0), q2.x, inc3);
    inc3 = fmaf(GB(sp2, 1), q2.y, inc3);
    inc3 = fmaf(GB(sp2, 2), q2.z, inc3);
    inc3 = fmaf(GB(sp2, 3), q2.w, inc3);
    inc3 = fmaf(GB(sp3, 0), q3.x, inc3);
    inc3 = fmaf(GB(sp3, 1), q3.y, inc3);
    inc3 = fmaf(GB(sp3, 2), q3.z, inc3);
    inc3 = fmaf(GB(sp3, 3), q3.w, inc3);
    #undef GB
    float nn = v3 + inc3;
    bool ss = nn >= 1.0f;
    v3 = ss ? 0.f : nn;
    acc += ss ? 1.0f : 0.0f;
}

// one scan step
template<int OFF>
__device__ __forceinline__ void step(
    int lane, unsigned w1a, unsigned w2a,
    float (&xw)[12], const float (&cwa)[7], const float (&cwb)[7],
    float& v1a, float& v1b,
    float& v20, float& v21, float& v22, float& v23,
    float& v3, float& acc,
    f32x4& Q0, f32x4& Q1, f32x4& Q2, f32x4& Q3,
    int& sp0, int& sp1, int& sp2, int& sp3,
    bool& anyp)
{
    // ---- layer 1: conv + IF (validated) ----
    float xca = 0.f, xcb = 0.f;
    #pragma unroll
    for (int k = 0; k < 7; ++k) {
        float xv = xw[OFF + k];
        xca = fmaf(xv, cwa[k], xca);
        xcb = fmaf(xv, cwb[k], xcb);
    }
    float na = v1a + xca, nb = v1b + xcb;
    bool sa = na >= 1.0f, sb = nb >= 1.0f;
    unsigned long long ma = __ballot(sa), mb = __ballot(sb);
    v1a = sa ? 0.f : na;
    v1b = sb ? 0.f : nb;

    // ---- layer 2: compaction-based gather, ascending c ----
    int Sa = __popcll(ma);
    int S  = Sa + __popcll(mb);
    f32x4 inc = {0.f, 0.f, 0.f, 0.f};

    if (__builtin_expect(S > 56, 0)) {
        // cold fallback: serial ascending-c path [R5-validated]
        if (anyp) { WAIT0; l3_consume(Q0,Q1,Q2,Q3, sp0,sp1,sp2,sp3, v3, acc); anyp = false; }
        unsigned long long lo = ma, hi = mb;
        while (lo | hi) {
            int c = pop_next(lo, hi);
            f32x4 t; ds_load4(t, w1a + ((unsigned)c << 10));
            WAIT0;
            inc += t;
        }
    } else if (S) {
        // push c+1 to slot[rank]; inactive lanes dump to in-range slot 63 (unused: S<=56)
        int ra4 = sa ? (mbcnt64(ma) << 2) : 252;
        int rb4 = sb ? ((Sa + mbcnt64(mb)) << 2) : 252;
        int da = __builtin_amdgcn_ds_permute(ra4, lane + 1);
        int db = __builtin_amdgcn_ds_permute(rb4, lane + 65);
        // broadcast slots 0..7 (compiler inserts the lgkm wait for da/db here)
        int c0, c1, c2, c3, c4, c5, c6, c7;
        #define SLOT(CS, s) do { \
            int ia = __builtin_amdgcn_readlane(da, s); \
            int ib = __builtin_amdgcn_readlane(db, s); \
            int v  = (s < Sa) ? ia : ib; \
            CS = (s < S) ? (v - 1) : 128; } while (0)
        SLOT(c0,0); SLOT(c1,1); SLOT(c2,2); SLOT(c3,3);
        SLOT(c4,4); SLOT(c5,5); SLOT(c6,6); SLOT(c7,7);
        #undef SLOT
        f32x4 g0, g1, g2, g3, g4, g5, g6, g7;
        ds_issue8(g0,g1,g2,g3,g4,g5,g6,g7,
                  w1a + ((unsigned)c0 << 10), w1a + ((unsigned)c1 << 10),
                  w1a + ((unsigned)c2 << 10), w1a + ((unsigned)c3 << 10),
                  w1a + ((unsigned)c4 << 10), w1a + ((unsigned)c5 << 10),
                  w1a + ((unsigned)c6 << 10), w1a + ((unsigned)c7 << 10));
        // consume deferred L3 in the gather shadow (q(t-1) drained by the permute wait)
        if (anyp) { l3_consume(Q0,Q1,Q2,Q3, sp0,sp1,sp2,sp3, v3, acc); anyp = false; }
        WAIT0;
        inc += g0; inc += g1; inc += g2; inc += g3;
        inc += g4; inc += g5; inc += g6; inc += g7;
        // rare overflow slots 8..S-1 (ascending)
        #pragma unroll 1
        for (int s = 8; s < S; ++s) {
            int ia = __builtin_amdgcn_readlane(da, s);
            int ib = __builtin_amdgcn_readlane(db, s);
            int c  = ((s < Sa) ? ia : ib) - 1;
            f32x4 t; ds_load4(t, w1a + ((unsigned)c << 10));
            WAIT0;
            inc += t;
        }
    } else {
        if (anyp) { WAIT0; l3_consume(Q0,Q1,Q2,Q3, sp0,sp1,sp2,sp3, v3, acc); anyp = false; }
    }

    // ---- IF layer 2 ----
    float n0 = v20 + inc.x, n1 = v21 + inc.y, n2 = v22 + inc.z, n3 = v23 + inc.w;
    bool s0 = n0 >= 1.0f, s1 = n1 >= 1.0f, s2 = n2 >= 1.0f, s3 = n3 >= 1.0f;
    v20 = s0 ? 0.f : n0; v21 = s1 ? 0.f : n1;
    v22 = s2 ? 0.f : n2; v23 = s3 ? 0.f : n3;

    // ---- layer 3: compaction + deferred issue ----
    int sub = (s0 ? 1 : 0) | (s1 ? 2 : 0) | (s2 ? 4 : 0) | (s3 ? 8 : 0);
    bool have = sub != 0;
    unsigned long long gm = __ballot(have);
    int S3 = __popcll(gm);
    if (S3) {
        int rk4 = have ? (mbcnt64(gm) << 2) : 252;
        int dv = __builtin_amdgcn_ds_permute(rk4, (lane + 1) | (sub << 8));
        if (__builtin_expect(S3 <= 4, 1)) {
            int v0 = __builtin_amdgcn_readlane(dv, 0);
            int v1 = __builtin_amdgcn_readlane(dv, 1);
            int v2 = __builtin_amdgcn_readlane(dv, 2);
            int v3i = __builtin_amdgcn_readlane(dv, 3);
            int l0 = (0 < S3) ? ((v0 & 255) - 1) : 64;
            int l1 = (1 < S3) ? ((v1 & 255) - 1) : 64;
            int l2 = (2 < S3) ? ((v2 & 255) - 1) : 64;
            int l3 = (3 < S3) ? ((v3i & 255) - 1) : 64;
            sp0 = (0 < S3) ? (v0 >> 8) : 0;
            sp1 = (1 < S3) ? (v1 >> 8) : 0;
            sp2 = (2 < S3) ? (v2 >> 8) : 0;
            sp3 = (3 < S3) ? (v3i >> 8) : 0;
            ds_issue4(Q0, Q1, Q2, Q3,
                      w2a + ((unsigned)l0 << 8), w2a + ((unsigned)l1 << 8),
                      w2a + ((unsigned)l2 << 8), w2a + ((unsigned)l3 << 8));
            anyp = true;
        } else {
            // rare: immediate exact-order path, slots ascending
            float inc3 = 0.f;
            #pragma unroll 1
            for (int s = 0; s < S3; ++s) {
                int v = __builtin_amdgcn_readlane(dv, s);
                int l = (v & 255) - 1;
                int sb3 = v >> 8;
                f32x4 q; ds_load4(q, w2a + ((unsigned)l << 8));
                WAIT0;
                inc3 = fmaf((sb3 & 1) ? 1.0f : 0.0f, q.x, inc3);
                inc3 = fmaf((sb3 & 2) ? 1.0f : 0.0f, q.y, inc3);
                inc3 = fmaf((sb3 & 4) ? 1.0f : 0.0f, q.z, inc3);
                inc3 = fmaf((sb3 & 8) ? 1.0f : 0.0f, q.w, inc3);
            }
            float nn = v3 + inc3;
            bool ss = nn >= 1.0f;
            v3 = ss ? 0.f : nn;
            acc += ss ? 1.0f : 0.0f;
        }
    }
}

// ---------------- main: one wave per batch ----------------
__global__ __launch_bounds__(256, 1)
void snn_main(const float* __restrict__ x,
              const float* __restrict__ convw,
              const float* __restrict__ w1Tg,
              const float* __restrict__ w2Qg,
              float* __restrict__ out) {
    extern __shared__ float lds[];
    const int b = blockIdx.x;
    const int tid = threadIdx.x;

    {   // stage: w1T (+ zero row), w2Q (+ zero group), x
        const float4* s4 = (const float4*)w1Tg;
        float4* d4 = (float4*)lds;
        for (int i = tid; i < 8192; i += 256) d4[i] = s4[i];
        if (tid < 64) d4[8192 + tid] = make_float4(0.f, 0.f, 0.f, 0.f);
        const float4* s2 = (const float4*)w2Qg;
        float4* d2 = (float4*)(lds + W2B / 4);
        for (int i = tid; i < 1040; i += 256) d2[i] = s2[i];
        float* xL = lds + XB / 4;
        for (int i = tid; i < 2064; i += 256) {
            int l = i - 3;
            xL[i] = (l >= 0 && l < TN) ? x[b * TN + l] : 0.0f;
        }
    }
    __syncthreads();
    if (tid >= 64) return;
    const int lane = tid;

    const unsigned ldsbase = (unsigned)(uintptr_t)(void*)lds;
    const unsigned w1a = ldsbase + W1B + (unsigned)lane * 16u;          // + (c<<10)
    const unsigned w2a = ldsbase + W2B + (unsigned)(lane & 15) * 16u;   // + (l<<8)

    float cwa[7], cwb[7];
    #pragma unroll
    for (int k = 0; k < 7; ++k) {
        cwa[k] = convw[lane * 7 + k];
        cwb[k] = convw[(lane + 64) * 7 + k];
    }

    float v1a = 0.f, v1b = 0.f;
    float v20 = 0.f, v21 = 0.f, v22 = 0.f, v23 = 0.f;   // h = 4*lane + j
    float v3 = 0.f, acc = 0.f;

    float xw[12];
    {
        const float* xL0 = lds + XB / 4;
        float4 f0 = *(const float4*)(xL0 + 0);
        float4 f1 = *(const float4*)(xL0 + 4);
        float4 f2 = *(const float4*)(xL0 + 8);
        xw[0]=f0.x; xw[1]=f0.y; xw[2]=f0.z; xw[3]=f0.w;
        xw[4]=f1.x; xw[5]=f1.y; xw[6]=f1.z; xw[7]=f1.w;
        xw[8]=f2.x; xw[9]=f2.y; xw[10]=f2.z; xw[11]=f2.w;
    }

    f32x4 Q0=0.f, Q1=0.f, Q2=0.f, Q3=0.f;
    int sp0=0, sp1=0, sp2=0, sp3=0;
    bool anyp = false;

    const float* xL = lds + XB / 4;
    #pragma unroll 1
    for (int tb = 0; tb < TN; tb += 4) {
        float4 fn = *(const float4*)(xL + tb + 12);   // prefetch next quad

        step<0>(lane, w1a, w2a, xw, cwa, cwb, v1a, v1b, v20, v21, v22, v23,
                v3, acc, Q0, Q1, Q2, Q3, sp0, sp1, sp2, sp3, anyp);
        step<1>(lane, w1a, w2a, xw, cwa, cwb, v1a, v1b, v20, v21, v22, v23,
                v3, acc, Q0, Q1, Q2, Q3, sp0, sp1, sp2, sp3, anyp);
        step<2>(lane, w1a, w2a, xw, cwa, cwb, v1a, v1b, v20, v21, v22, v23,
                v3, acc, Q0, Q1, Q2, Q3, sp0, sp1, sp2, sp3, anyp);
        step<3>(lane, w1a, w2a, xw, cwa, cwb, v1a, v1b, v20, v21, v22, v23,
                v3, acc, Q0, Q1, Q2, Q3, sp0, sp1, sp2, sp3, anyp);

        #pragma unroll
        for (int i = 0; i < 8; ++i) xw[i] = xw[i + 4];
        xw[8] = fn.x; xw[9] = fn.y; xw[10] = fn.z; xw[11] = fn.w;
    }

    if (anyp) {
        WAIT0;
        l3_consume(Q0, Q1, Q2, Q3, sp0, sp1, sp2, sp3, v3, acc);
    }

    if (lane < 10) out[b * 10 + lane] = acc * (1.0f / 2048.0f);
}

extern "C" void kernel_launch(void* const* d_in, const int* in_sizes, int n_in,
                              void* d_out, int out_size, void* d_ws, size_t ws_size,
                              hipStream_t stream) {
    const float* x     = (const float*)d_in[0];
    const float* convw = (const float*)d_in[1];
    const float* w1    = (const float*)d_in[2];
    const float* w2    = (const float*)d_in[3];
    float* w1T = (float*)d_ws;                 // 131072 B
    float* w2Q = (float*)d_ws + 32768;         //  16640 B

    prep_kernel<<<33, 256, 0, stream>>>(w1, w2, w1T, w2Q);

    const size_t ldsz = 156992;   // bytes
    (void)hipFuncSetAttribute(reinterpret_cast<const void*>(snn_main),
                              hipFuncAttributeMaxDynamicSharedMemorySize, (int)ldsz);
    snn_main<<<128, 256, ldsz, stream>>>(x, convw, w1T, w2Q, (float*)d_out);
}